// Round 6
// baseline (346.324 us; speedup 1.0000x reference)
//
#include <hip/hip_runtime.h>
#include <cstdint>

// AdaptiveLoss: adaptive-softmax NLL.  7 launches:
//   1. cvt_bf16   : f32->bf16 for all operands.
//   2. gemm_all   : proj GEMMs (bf16 C -> Hact), grid (8,8).
//   3. gemm_8p    : deep-K segments (head K=1024, c0 K=512, c1 K=256) as
//                   256x256-tile 8-wave phase-split GEMM (dbuf LDS 128KB,
//                   raw-barrier phases, loads in flight across phases,
//                   vmcnt(0) drain once per K-tile) -> sum-exp partials+gates.
//   4. gemm_all   : c2+c3 (shallow K) 128x128 proven structure, swz.
//   5. lse_reduce : wave-per-row over [tile][row] partials.
//   6. gather_rows: per-target log-prob + fused row loss.
//   7. final_sum.
// R6 vs R5 (311.8 us): deep-K segs (~65 us of the 94.7 us mega) ported to the
// 256^2 8-phase structure (regime-gate: only 256^2+phase-split+counted-drain
// breaks the 2-phase ceiling; 128^2 variants all null). c2/c3 kept in the
// unchanged 128^2 kernel for risk containment.

typedef unsigned short u16;
typedef __attribute__((ext_vector_type(4))) float f32x4;
typedef __attribute__((ext_vector_type(8))) __bf16 bf16x8;
typedef __attribute__((ext_vector_type(4))) unsigned int u32x4;

__device__ __forceinline__ u16 f2bf(float f){
  unsigned u = __float_as_uint(f);
  u += 0x7FFFu + ((u >> 16) & 1u);   // RNE
  return (u16)(u >> 16);
}

__device__ __forceinline__ float wave_sum(float v){
  #pragma unroll
  for (int d = 1; d < 64; d <<= 1) v += __shfl_xor(v, d, 64);
  return v;
}

// dot: a from LDS, b from global, len multiple of 8 (<=1024), full-wave result
__device__ __forceinline__ float wave_dot_l(const u16* a_lds, const u16* b, int len, int lane){
  float s = 0.f;
  for (int k = lane*8; k < len; k += 512){
    u32x4 va = *(const u32x4*)(a_lds + k);
    u32x4 vb = *(const u32x4*)(b + k);
    #pragma unroll
    for (int i = 0; i < 4; i++){
      unsigned ua = va[i], ub = vb[i];
      s = fmaf(__uint_as_float(ua << 16),        __uint_as_float(ub << 16),        s);
      s = fmaf(__uint_as_float(ua & 0xFFFF0000u), __uint_as_float(ub & 0xFFFF0000u), s);
    }
  }
  return wave_sum(s);
}

// async global->LDS, 16B per lane. LDS dest must be wave-uniform base
// (HW adds lane*16); global src is per-lane (carries the XOR pre-swizzle).
__device__ __forceinline__ void gload_lds16(const void* g, void* l){
  __builtin_amdgcn_global_load_lds(
      (const __attribute__((address_space(1))) unsigned int*)g,
      (__attribute__((address_space(3))) unsigned int*)l, 16, 0, 0);
}

// ---------------- convert f32 -> bf16 (10 segments, one launch) ----------------
struct CvtSeg { const float* src; u16* dst; unsigned start; }; // start in 8-elem chunks
struct CvtTab { CvtSeg s[10]; unsigned total; };

__global__ __launch_bounds__(256) void cvt_bf16(CvtTab t){
  unsigned stride = gridDim.x * blockDim.x;
  for (unsigned c = blockIdx.x*blockDim.x + threadIdx.x; c < t.total; c += stride){
    int si = 0;
    #pragma unroll
    for (int i = 1; i < 10; i++) if (c >= t.s[i].start) si = i;
    unsigned lo = c - t.s[si].start;
    const float4* sp = (const float4*)t.s[si].src + (size_t)lo*2;
    float4 f0 = sp[0], f1 = sp[1];
    uint4 d;
    d.x = (unsigned)f2bf(f0.x) | ((unsigned)f2bf(f0.y) << 16);
    d.y = (unsigned)f2bf(f0.z) | ((unsigned)f2bf(f0.w) << 16);
    d.z = (unsigned)f2bf(f1.x) | ((unsigned)f2bf(f1.y) << 16);
    d.w = (unsigned)f2bf(f1.z) | ((unsigned)f2bf(f1.w) << 16);
    ((uint4*)t.s[si].dst)[lo] = d;
  }
}

// ------- unified GEMM: C = A[MxK] * B[NxK]^T, 128x128 tile, BK=64 -------
// (unchanged proven structure; used for proj + c2/c3)
struct GSeg { const u16* A; const u16* B; float* part; u16* C; float* gates;
              int lda, N, K, ntiles, tileStart, ldc; };
struct GTab { GSeg seg[5]; int nseg; int swz; };

__global__ __launch_bounds__(256, 4) void gemm_all(GTab tab){
  __shared__ __attribute__((aligned(16))) u16 ldsA[128*64];
  __shared__ __attribute__((aligned(16))) u16 ldsB[128*64];
  __shared__ float msLds[128][2];

  int bx = blockIdx.x, by = blockIdx.y;
  if (tab.swz){
    int flat = by * 8 + bx;
    int xcd = flat & 7, j = flat >> 3;
    by = (j >> 3) * 8 + xcd;
    bx = j & 7;
    if (by >= (int)gridDim.y){ by = j; bx = xcd; }  // bijective tail patch
  }

  int s = 0;
  #pragma unroll
  for (int i = 1; i < 5; i++)
    if (i < tab.nseg && by >= tab.seg[i].tileStart) s = i;
  const u16* Ab = tab.seg[s].A;
  const u16* Bb = tab.seg[s].B;
  float* part   = tab.seg[s].part;
  u16* Cc       = tab.seg[s].C;
  float* gatesp = tab.seg[s].gates;
  int lda = tab.seg[s].lda, N = tab.seg[s].N, K = tab.seg[s].K;
  int ldc = tab.seg[s].ldc;
  int tileN = by - tab.seg[s].tileStart;
  int n0 = tileN * 128;
  int row0 = bx * 128;

  int tid = threadIdx.x;
  int wid = tid >> 6, lane = tid & 63;
  int wr = wid >> 1, wc = wid & 1;
  int qr = lane >> 4, ln = lane & 15;

  const char* baseA = (const char*)(Ab + (size_t)row0*lda);
  const char* baseB = (const char*)Bb;
  unsigned offA[4], offB[4];
  #pragma unroll
  for (int t = 0; t < 4; t++){
    int c = t*256 + tid, row = c >> 3, jj = (c & 7) ^ (row & 7);
    offA[t] = (unsigned)(row*lda + jj*8) * 2u;
    int nr = n0 + row; if (nr >= N) nr = N - 1;
    offB[t] = (unsigned)(nr*K + jj*8) * 2u;
  }

  f32x4 acc[4][4];
  const f32x4 zero = {0.f, 0.f, 0.f, 0.f};
  #pragma unroll
  for (int i = 0; i < 4; i++)
    #pragma unroll
    for (int j = 0; j < 4; j++) acc[i][j] = zero;

  int nkt = K >> 6;
  for (int kt = 0; kt < nkt; kt++){
    __syncthreads();
    unsigned kb = (unsigned)kt * 128u;
    #pragma unroll
    for (int t = 0; t < 4; t++){
      gload_lds16(baseA + offA[t] + kb, (char*)ldsA + (size_t)(t*256 + tid)*16);
      gload_lds16(baseB + offB[t] + kb, (char*)ldsB + (size_t)(t*256 + tid)*16);
    }
    __syncthreads();
    #pragma unroll
    for (int ks = 0; ks < 2; ks++){
      bf16x8 av[4], bv[4];
      #pragma unroll
      for (int mt = 0; mt < 4; mt++){
        int rl = wr*64 + mt*16 + ln;
        int ch = rl*8 + ((ks*4 + qr) ^ (rl & 7));
        av[mt] = *(const bf16x8*)((const char*)ldsA + ch*16);
      }
      #pragma unroll
      for (int nt = 0; nt < 4; nt++){
        int rl = wc*64 + nt*16 + ln;
        int ch = rl*8 + ((ks*4 + qr) ^ (rl & 7));
        bv[nt] = *(const bf16x8*)((const char*)ldsB + ch*16);
      }
      #pragma unroll
      for (int mt = 0; mt < 4; mt++)
        #pragma unroll
        for (int nt = 0; nt < 4; nt++)
          acc[mt][nt] = __builtin_amdgcn_mfma_f32_16x16x32_bf16(av[mt], bv[nt], acc[mt][nt], 0, 0, 0);
    }
  }

  if (part){
    #pragma unroll
    for (int mt = 0; mt < 4; mt++){
      #pragma unroll
      for (int r = 0; r < 4; r++){
        float ss = 0.f;
        #pragma unroll
        for (int nt = 0; nt < 4; nt++){
          int col = n0 + wc*64 + nt*16 + ln;
          if (col < N){
            float v = acc[mt][nt][r];
            ss += __expf(v);
            if (gatesp && col >= 10000){
              int row = row0 + wr*64 + mt*16 + qr*4 + r;
              gatesp[row*4 + (col - 10000)] = v;
            }
          }
        }
        ss += __shfl_xor(ss, 1, 64);
        ss += __shfl_xor(ss, 2, 64);
        ss += __shfl_xor(ss, 4, 64);
        ss += __shfl_xor(ss, 8, 64);
        if (ln == 0) msLds[wr*64 + mt*16 + qr*4 + r][wc] = ss;
      }
    }
    __syncthreads();
    if (tid < 128)
      part[(size_t)tileN*1024 + row0 + tid] = msLds[tid][0] + msLds[tid][1];
  } else {
    #pragma unroll
    for (int mt = 0; mt < 4; mt++)
      #pragma unroll
      for (int nt = 0; nt < 4; nt++)
        #pragma unroll
        for (int r = 0; r < 4; r++){
          int col = n0 + wc*64 + nt*16 + ln;
          if (col < N){
            int row = row0 + wr*64 + mt*16 + qr*4 + r;
            Cc[(size_t)row*ldc + col] = f2bf(acc[mt][nt][r]);
          }
        }
  }
}

// ------- deep-K 256x256 8-wave phase-split GEMM (head/c0/c1) -------
// 512 thr = 8 waves (2M x 4N); per-wave out 128x64 (acc[8][4]); BK=64;
// LDS: dbuf x (A 32KB + B 32KB) = 128KB -> 1 block/CU. Per K-tile: issue 8
// gload_lds for t+1 -> 4 {ds_read, raw-barrier, setprio, 16 MFMA, barrier}
// phases on tile t -> sched_barrier + vmcnt(0) + barrier. Loads in flight
// across all phases; drained once per K-tile after 4 phases of compute.
struct P8Seg { const u16* A; const u16* B; float* part; float* gates;
               int lda, N, K, tileStart; };
struct P8Tab { P8Seg seg[3]; };

#define MFMA16(MH, NH)                                                        \
  {                                                                           \
    _Pragma("unroll")                                                         \
    for (int am = 0; am < 4; am++)                                            \
      _Pragma("unroll")                                                       \
      for (int bn = 0; bn < 2; bn++)                                          \
        _Pragma("unroll")                                                     \
        for (int ks = 0; ks < 2; ks++)                                        \
          acc[(MH)*4+am][(NH)*2+bn] = __builtin_amdgcn_mfma_f32_16x16x32_bf16(\
              af[am][ks], bf[(NH)*2+bn][ks], acc[(MH)*4+am][(NH)*2+bn], 0,0,0);\
  }

__global__ __launch_bounds__(512, 2) void gemm_8p(P8Tab tab){
  __shared__ __attribute__((aligned(16))) u16 ldsA[2][16384];
  __shared__ __attribute__((aligned(16))) u16 ldsB[2][16384];

  // padded bijective XCD swizzle: grid (4,160) = 640 slots, 636 active.
  // byp === xcd (mod 8): col-tile stripes balance K-depth across XCDs.
  int flat = blockIdx.y*4 + blockIdx.x;
  int xcd = flat & 7, j = flat >> 3;         // j in 0..79
  int bxp = j & 3;
  int byp = (j >> 2)*8 + xcd;                // 0..159
  if (byp >= 159) return;                    // 4 pad slots idle

  int s = 0;
  #pragma unroll
  for (int i = 1; i < 3; i++) if (byp >= tab.seg[i].tileStart) s = i;
  const u16* Ab = tab.seg[s].A;
  const u16* Bb = tab.seg[s].B;
  float* part   = tab.seg[s].part;
  float* gatesp = tab.seg[s].gates;
  int lda = tab.seg[s].lda, N = tab.seg[s].N, K = tab.seg[s].K;
  int tileN = byp - tab.seg[s].tileStart;
  int n0 = tileN * 256;
  int row0 = bxp * 256;

  int tid = threadIdx.x;
  int wid = tid >> 6, lane = tid & 63;
  int wm = wid >> 2, wn = wid & 3;
  int qr = lane >> 4, ln = lane & 15;

  // staging: 2048 x 16B chunks per matrix per K-tile, 4 per thread;
  // XOR swizzle on the GLOBAL source k-chunk, LDS linear (both-sides rule).
  const char* baseA = (const char*)(Ab + (size_t)row0*lda);
  const char* baseB = (const char*)Bb;
  unsigned offA[4], offB[4];
  #pragma unroll
  for (int i = 0; i < 4; i++){
    int c = i*512 + tid, row = c >> 3, jj = (c & 7) ^ (row & 7);
    offA[i] = (unsigned)(row*lda + jj*8) * 2u;
    int nr = n0 + row; if (nr >= N) nr = N - 1;   // clamp; masked in epilogue
    offB[i] = (unsigned)(nr*K + jj*8) * 2u;
  }

  f32x4 acc[8][4];
  const f32x4 zero = {0.f, 0.f, 0.f, 0.f};
  #pragma unroll
  for (int i = 0; i < 8; i++)
    #pragma unroll
    for (int jn = 0; jn < 4; jn++) acc[i][jn] = zero;

  auto STAGE = [&](int t, int nb){
    unsigned kb = (unsigned)t * 128u;
    #pragma unroll
    for (int i = 0; i < 4; i++){
      int c = i*512 + tid;
      gload_lds16(baseA + offA[i] + kb, (char*)&ldsA[nb][0] + (size_t)c*16);
      gload_lds16(baseB + offB[i] + kb, (char*)&ldsB[nb][0] + (size_t)c*16);
    }
  };

  int nkt = K >> 6;
  STAGE(0, 0);
  __syncthreads();                        // full drain: tile 0 ready

  int cur = 0;
  for (int t = 0; t < nkt; ++t){
    if (t + 1 < nkt) STAGE(t + 1, cur ^ 1);   // fly across all 4 phases
    const char* bA = (const char*)&ldsA[cur][0];
    const char* bB = (const char*)&ldsB[cur][0];
    bf16x8 af[4][2], bf[4][2];

    // phase 1 reads: A-quadrant mh=0 (8) + all B (8)
    #pragma unroll
    for (int am = 0; am < 4; am++)
      #pragma unroll
      for (int ks = 0; ks < 2; ks++){
        int rl = wm*128 + am*16 + ln;
        af[am][ks] = *(const bf16x8*)(bA + ((size_t)(rl*8 + ((ks*4+qr) ^ (rl&7))))*16);
      }
    #pragma unroll
    for (int bn = 0; bn < 4; bn++)
      #pragma unroll
      for (int ks = 0; ks < 2; ks++){
        int rl = wn*64 + bn*16 + ln;
        bf[bn][ks] = *(const bf16x8*)(bB + ((size_t)(rl*8 + ((ks*4+qr) ^ (rl&7))))*16);
      }
    __builtin_amdgcn_s_barrier();
    __builtin_amdgcn_s_setprio(1);
    MFMA16(0, 0)
    __builtin_amdgcn_s_setprio(0);
    __builtin_amdgcn_s_barrier();
    // phase 2 (mh0, nh1): no new reads
    __builtin_amdgcn_s_setprio(1);
    MFMA16(0, 1)
    __builtin_amdgcn_s_setprio(0);
    __builtin_amdgcn_s_barrier();
    // phase 3 reads: A-quadrant mh=1 (8)
    #pragma unroll
    for (int am = 0; am < 4; am++)
      #pragma unroll
      for (int ks = 0; ks < 2; ks++){
        int rl = wm*128 + 64 + am*16 + ln;
        af[am][ks] = *(const bf16x8*)(bA + ((size_t)(rl*8 + ((ks*4+qr) ^ (rl&7))))*16);
      }
    __builtin_amdgcn_s_barrier();
    __builtin_amdgcn_s_setprio(1);
    MFMA16(1, 0)
    __builtin_amdgcn_s_setprio(0);
    __builtin_amdgcn_s_barrier();
    // phase 4 (mh1, nh1)
    __builtin_amdgcn_s_setprio(1);
    MFMA16(1, 1)
    __builtin_amdgcn_s_setprio(0);
    __builtin_amdgcn_sched_barrier(0);
    if (t + 1 < nkt){
      asm volatile("s_waitcnt vmcnt(0)" ::: "memory");   // own t+1 loads done
    }
    __builtin_amdgcn_s_barrier();          // all waves' loads done
    cur ^= 1;
  }

  // epilogue: sum-exp per row over this block's 256 cols; gates for head
  __syncthreads();                         // fence before overlaying ldsA
  float* msLds = (float*)&ldsA[0][0];      // [256][4]
  #pragma unroll
  for (int m = 0; m < 8; m++){
    #pragma unroll
    for (int r = 0; r < 4; r++){
      float ss = 0.f;
      #pragma unroll
      for (int n = 0; n < 4; n++){
        int col = n0 + wn*64 + n*16 + ln;
        if (col < N){
          float v = acc[m][n][r];
          ss += __expf(v);
          if (gatesp && col >= 10000){
            int row = row0 + wm*128 + m*16 + qr*4 + r;
            gatesp[row*4 + (col - 10000)] = v;
          }
        }
      }
      ss += __shfl_xor(ss, 1, 64);
      ss += __shfl_xor(ss, 2, 64);
      ss += __shfl_xor(ss, 4, 64);
      ss += __shfl_xor(ss, 8, 64);
      if (ln == 0) msLds[(wm*128 + m*16 + qr*4 + r)*4 + wn] = ss;
    }
  }
  __syncthreads();
  if (tid < 256){
    const float* p = msLds + tid*4;
    part[(size_t)tileN*1024 + row0 + tid] = p[0] + p[1] + p[2] + p[3];
  }
}

// ---------------- LSE finalize ----------------
struct LseTab { const float* base[5]; int ntiles[5]; float* lse; };

__global__ __launch_bounds__(256) void lse_reduce(LseTab t){
  int widx = blockIdx.x*4 + (threadIdx.x >> 6);   // 5120 waves: mat*1024 + row
  int lane = threadIdx.x & 63;
  int mat = widx >> 10, row = widx & 1023;
  const float* p = t.base[mat];
  int n = t.ntiles[mat];
  float s = 0.f;
  for (int i = lane; i < n; i += 64) s += p[(size_t)i*1024 + row];
  s = wave_sum(s);
  if (lane == 0) t.lse[mat*1024 + row] = __logf(s);
}

// ------- row-centric per-target log-prob + fused row loss -------
struct GatherArgs {
  const u16* Xb; const u16* Hb; const u16* Hact; const u16* Ob;
  const float* lse; const float* gates; const int* targets;
  const float* discard; float* psamp;
};

__global__ __launch_bounds__(256) void gather_rows(GatherArgs g){
  __shared__ __attribute__((aligned(16))) u16 xr[1024];
  __shared__ __attribute__((aligned(16))) u16 hr[960];
  __shared__ __attribute__((aligned(16))) int tg[128];
  __shared__ float ls[5], gs[4];
  __shared__ float lpv[128];
  __shared__ float sa[2], sw[2];

  int b = blockIdx.x;
  int tid = threadIdx.x;
  int w = tid >> 6, lane = tid & 63;

  if (tid < 128) ((u32x4*)xr)[tid] = ((const u32x4*)(g.Xb + (size_t)b*1024))[tid];
  else if (tid < 248) ((u32x4*)hr)[tid-128] = ((const u32x4*)(g.Hact + (size_t)b*960))[tid-128];
  if (tid < 32) ((u32x4*)tg)[tid] = ((const u32x4*)(g.targets + (size_t)b*128))[tid];
  if (tid < 5) ls[tid] = g.lse[tid*1024 + b];
  if (tid < 4) gs[tid] = g.gates[b*4 + tid];
  __syncthreads();

  for (int t = 0; t < 32; t++){
    int ti = w*32 + t;
    int v = tg[ti];                         // wave-uniform
    float val;
    if (v < 10000){
      float logit = wave_dot_l(xr, g.Hb + (size_t)v*1024, 1024, lane);
      val = logit - ls[0];
    } else {
      int c, off, psz, hoff; size_t oboff;
      if      (v < 20000){ c=0; off=10000; psz=512; hoff=0;   oboff=0; }
      else if (v < 40000){ c=1; off=20000; psz=256; hoff=512; oboff=5120000; }
      else if (v < 80000){ c=2; off=40000; psz=128; hoff=768; oboff=10240000; }
      else               { c=3; off=80000; psz=64;  hoff=896; oboff=15360000; }
      float logit = wave_dot_l(hr + hoff, g.Ob + oboff + (size_t)(v - off)*psz, psz, lane);
      val = gs[c] - ls[0] + logit - ls[c + 1];
    }
    if (lane == 0) lpv[ti] = val;
  }
  __syncthreads();

  if (tid < 128){
    int v = tg[tid];
    float wt = 1.0f - g.discard[v];
    float a  = -lpv[tid] * wt;
    float as = wave_sum(a), ws = wave_sum(wt);
    if (lane == 0){ sa[w] = as; sw[w] = ws; }
  }
  __syncthreads();
  if (tid == 0) g.psamp[b] = (sa[0] + sa[1]) / (sw[0] + sw[1]);
}

__global__ __launch_bounds__(256) void final_sum(const float* psamp, float* out){
  float s = 0.f;
  for (int i = threadIdx.x; i < 1024; i += 256) s += psamp[i];
  s = wave_sum(s);
  __shared__ float sb[4];
  if ((threadIdx.x & 63) == 0) sb[threadIdx.x >> 6] = s;
  __syncthreads();
  if (threadIdx.x == 0) out[0] = (sb[0] + sb[1] + sb[2] + sb[3]) / (1024.0f + 1e-5f);
}

// ---------------- host ----------------
extern "C" void kernel_launch(void* const* d_in, const int* in_sizes, int n_in,
                              void* d_out, int out_size, void* d_ws, size_t ws_size,
                              hipStream_t stream){
  (void)in_sizes; (void)n_in; (void)out_size; (void)ws_size;
  const float* features = (const float*)d_in[0];
  const float* head_w   = (const float*)d_in[1];
  const float* proj[4]  = {(const float*)d_in[2], (const float*)d_in[4],
                           (const float*)d_in[6], (const float*)d_in[8]};
  const float* outw[4]  = {(const float*)d_in[3], (const float*)d_in[5],
                           (const float*)d_in[7], (const float*)d_in[9]};
  const float* discard  = (const float*)d_in[10];
  const int*   targets  = (const int*)d_in[11];
  float* out = (float*)d_out;

  char* wsp = (char*)d_ws;
  size_t off = 0;
  auto carve = [&](size_t bytes)->char*{
    char* p = wsp + off; off += (bytes + 255) & ~(size_t)255; return p;
  };
  u16* Xb     = (u16*)carve(1024ull*1024*2);
  u16* Hb     = (u16*)carve(10004ull*1024*2);
  u16* Pb     = (u16*)carve(960ull*1024*2);
  u16* Ob     = (u16*)carve(16640000ull*2);
  u16* Hact   = (u16*)carve(1024ull*960*2);
  float* part = (float*)carve(803840ull*4);
  float* lse  = (float*)carve(5*1024*4);
  float* gates= (float*)carve(4096*4);
  float* psamp= (float*)carve(1024*4);

  // launch 1: convert all f32 operands to bf16
  CvtTab ct{};
  const float* srcs[10] = {features, head_w, proj[0], proj[1], proj[2], proj[3],
                           outw[0], outw[1], outw[2], outw[3]};
  u16* dsts[10] = {Xb, Hb, Pb, Pb + 512*1024, Pb + 768*1024, Pb + 896*1024,
                   Ob, Ob + 5120000, Ob + 10240000, Ob + 15360000};
  unsigned counts[10] = {1048576u, 10244096u, 524288u, 262144u, 131072u, 65536u,
                         5120000u, 5120000u, 5120000u, 1280000u};
  unsigned pre = 0;
  for (int i = 0; i < 10; i++){
    ct.s[i].src = srcs[i]; ct.s[i].dst = dsts[i]; ct.s[i].start = pre;
    pre += counts[i] / 8;
  }
  ct.total = pre;
  cvt_bf16<<<dim3(4096), dim3(256), 0, stream>>>(ct);

  // part layout: [tile][1024 rows]; tiles: head 40 (256-wide), c0 40, c1 79,
  // c2 313 (128-wide), c3 157 (128-wide)
  float* pHead = part;
  float* pC0 = part + 40960;    // 40*1024
  float* pC1 = part + 81920;    // +40*1024
  float* pC2 = part + 162816;   // +79*1024
  float* pC3 = part + 483328;   // +313*1024

  // launch 2: proj GEMMs (bf16 C -> Hact)
  GTab tp{};
  tp.nseg = 4; tp.swz = 0;
  tp.seg[0] = {Xb, Pb,            nullptr, Hact,       nullptr, 1024, 512, 1024, 4, 0, 960};
  tp.seg[1] = {Xb, Pb + 512*1024, nullptr, Hact + 512, nullptr, 1024, 256, 1024, 2, 4, 960};
  tp.seg[2] = {Xb, Pb + 768*1024, nullptr, Hact + 768, nullptr, 1024, 128, 1024, 1, 6, 960};
  tp.seg[3] = {Xb, Pb + 896*1024, nullptr, Hact + 896, nullptr, 1024, 64,  1024, 1, 7, 960};
  gemm_all<<<dim3(8, 8), dim3(256), 0, stream>>>(tp);

  // launch 3: deep-K (head + c0 + c1) via 256^2 8-phase kernel
  P8Tab t8{};
  t8.seg[0] = {Xb,         Hb,           pHead, gates,   1024, 10004, 1024, 0};
  t8.seg[1] = {Hact,       Ob,           pC0,   nullptr, 960,  10000, 512,  40};
  t8.seg[2] = {Hact + 512, Ob + 5120000, pC1,   nullptr, 960,  20000, 256,  80};
  gemm_8p<<<dim3(4, 160), dim3(512), 0, stream>>>(t8);

  // launch 4: c2 + c3 via proven 128^2 kernel
  GTab tm{};
  tm.nseg = 2; tm.swz = 1;
  tm.seg[0] = {Hact + 768, Ob + 10240000, pC2, nullptr, nullptr, 960, 40000, 128, 313, 0,   0};
  tm.seg[1] = {Hact + 896, Ob + 15360000, pC3, nullptr, nullptr, 960, 20000, 64,  157, 313, 0};
  gemm_all<<<dim3(8, 470), dim3(256), 0, stream>>>(tm);

  // launch 5: LSE finalize
  LseTab lt{};
  lt.base[0] = pHead; lt.base[1] = pC0; lt.base[2] = pC1; lt.base[3] = pC2; lt.base[4] = pC3;
  lt.ntiles[0] = 40; lt.ntiles[1] = 40; lt.ntiles[2] = 79; lt.ntiles[3] = 313; lt.ntiles[4] = 157;
  lt.lse = lse;
  lse_reduce<<<dim3(1280), dim3(256), 0, stream>>>(lt);

  // launch 6: gather (target log-probs + fused row loss)
  GatherArgs ga{Xb, Hb, Hact, Ob, lse, gates, targets, discard, psamp};
  gather_rows<<<dim3(1024), dim3(256), 0, stream>>>(ga);

  // launch 7: final reduction
  final_sum<<<dim3(1), dim3(256), 0, stream>>>(psamp, out);
}

// Round 7
// 299.719 us; speedup vs baseline: 1.1555x; 1.1555x over previous
//
#include <hip/hip_runtime.h>
#include <cstdint>

// AdaptiveLoss: adaptive-softmax NLL.  6 launches (R5 composition + new gather):
//   1. cvt_bf16   : f32->bf16 for all operands (10 segments, 4096 blocks).
//   2. gemm_all   : proj GEMMs (bf16 C -> Hact), grid (8,8).
//   3. gemm_all   : single mega (head + c0..c3, 6280 blocks) -> sum-exp
//                   partials part[tile][row] + head gates.
//   4. lse_reduce : wave-per-row (5120 waves) over [tile][row] partials.
//   5. gather_rows: 16-lane-group per-target log-prob (branchless uniform
//                   8-iter dot; 4x fewer serial dots per wave) + fused row loss.
//   6. final_sum.
// R7 vs R6 (346.3 us): gemm_8p reverted (453 TF < mega's inline 642 TF;
// occupancy 18%, the counted-vmcnt pipeline was not reproduced). Non-mega
// time is ~217 us with no kernel >65 us -> gather (~60-90 us est) is the
// biggest hidden cost; its 32-serial-wave-dots structure replaced by
// 16-lane-group x 8-target uniform loop (no branch divergence, clamped
// addresses make short rows L1-cheap).

typedef unsigned short u16;
typedef __attribute__((ext_vector_type(4))) float f32x4;
typedef __attribute__((ext_vector_type(8))) __bf16 bf16x8;
typedef __attribute__((ext_vector_type(4))) unsigned int u32x4;

__device__ __forceinline__ u16 f2bf(float f){
  unsigned u = __float_as_uint(f);
  u += 0x7FFFu + ((u >> 16) & 1u);   // RNE
  return (u16)(u >> 16);
}

__device__ __forceinline__ float wave_sum(float v){
  #pragma unroll
  for (int d = 1; d < 64; d <<= 1) v += __shfl_xor(v, d, 64);
  return v;
}

// async global->LDS, 16B per lane. LDS dest must be wave-uniform base
// (HW adds lane*16); global src is per-lane (carries the XOR pre-swizzle).
__device__ __forceinline__ void gload_lds16(const void* g, void* l){
  __builtin_amdgcn_global_load_lds(
      (const __attribute__((address_space(1))) unsigned int*)g,
      (__attribute__((address_space(3))) unsigned int*)l, 16, 0, 0);
}

// ---------------- convert f32 -> bf16 (10 segments, one launch) ----------------
struct CvtSeg { const float* src; u16* dst; unsigned start; }; // start in 8-elem chunks
struct CvtTab { CvtSeg s[10]; unsigned total; };

__global__ __launch_bounds__(256) void cvt_bf16(CvtTab t){
  unsigned stride = gridDim.x * blockDim.x;
  for (unsigned c = blockIdx.x*blockDim.x + threadIdx.x; c < t.total; c += stride){
    int si = 0;
    #pragma unroll
    for (int i = 1; i < 10; i++) if (c >= t.s[i].start) si = i;
    unsigned lo = c - t.s[si].start;
    const float4* sp = (const float4*)t.s[si].src + (size_t)lo*2;
    float4 f0 = sp[0], f1 = sp[1];
    uint4 d;
    d.x = (unsigned)f2bf(f0.x) | ((unsigned)f2bf(f0.y) << 16);
    d.y = (unsigned)f2bf(f0.z) | ((unsigned)f2bf(f0.w) << 16);
    d.z = (unsigned)f2bf(f1.x) | ((unsigned)f2bf(f1.y) << 16);
    d.w = (unsigned)f2bf(f1.z) | ((unsigned)f2bf(f1.w) << 16);
    ((uint4*)t.s[si].dst)[lo] = d;
  }
}

// ------- unified GEMM: C = A[MxK] * B[NxK]^T, 128x128 tile, BK=64 -------
// 4 waves 2x2; global_load_lds staging. part!=null -> per-(tile,row) sum-exp
// partials (layout part[tile*1024 + row], contiguous per block); else bf16 C
// store (ldc). gates!=null (head): cols>=10000 -> gates[row*4+i].
struct GSeg { const u16* A; const u16* B; float* part; u16* C; float* gates;
              int lda, N, K, ntiles, tileStart, ldc; };
struct GTab { GSeg seg[5]; int nseg; int swz; };

__global__ __launch_bounds__(256, 4) void gemm_all(GTab tab){
  __shared__ __attribute__((aligned(16))) u16 ldsA[128*64];
  __shared__ __attribute__((aligned(16))) u16 ldsB[128*64];
  __shared__ float msLds[128][2];

  int bx = blockIdx.x, by = blockIdx.y;
  if (tab.swz){
    // bijective XCD swizzle, grid (8, nby): hardware XCD ~ flat%8.
    int flat = by * 8 + bx;
    int xcd = flat & 7, j = flat >> 3;
    by = (j >> 3) * 8 + xcd;
    bx = j & 7;
    if (by >= (int)gridDim.y){ by = j; bx = xcd; }  // bijective tail patch
  }

  int s = 0;
  #pragma unroll
  for (int i = 1; i < 5; i++)
    if (i < tab.nseg && by >= tab.seg[i].tileStart) s = i;
  const u16* Ab = tab.seg[s].A;
  const u16* Bb = tab.seg[s].B;
  float* part   = tab.seg[s].part;
  u16* Cc       = tab.seg[s].C;
  float* gatesp = tab.seg[s].gates;
  int lda = tab.seg[s].lda, N = tab.seg[s].N, K = tab.seg[s].K;
  int ldc = tab.seg[s].ldc;
  int tileN = by - tab.seg[s].tileStart;
  int n0 = tileN * 128;
  int row0 = bx * 128;

  int tid = threadIdx.x;
  int wid = tid >> 6, lane = tid & 63;
  int wr = wid >> 1, wc = wid & 1;
  int qr = lane >> 4, ln = lane & 15;

  // staging: 1024 chunks (16B) per matrix, 4 per thread; XOR swizzle applied
  // to the GLOBAL source k-chunk, LDS written linearly.
  const char* baseA = (const char*)(Ab + (size_t)row0*lda);
  const char* baseB = (const char*)Bb;
  unsigned offA[4], offB[4];
  #pragma unroll
  for (int t = 0; t < 4; t++){
    int c = t*256 + tid, row = c >> 3, jj = (c & 7) ^ (row & 7);
    offA[t] = (unsigned)(row*lda + jj*8) * 2u;
    int nr = n0 + row; if (nr >= N) nr = N - 1;    // clamp; masked in epilogue
    offB[t] = (unsigned)(nr*K + jj*8) * 2u;
  }

  f32x4 acc[4][4];
  const f32x4 zero = {0.f, 0.f, 0.f, 0.f};
  #pragma unroll
  for (int i = 0; i < 4; i++)
    #pragma unroll
    for (int j = 0; j < 4; j++) acc[i][j] = zero;

  int nkt = K >> 6;
  for (int kt = 0; kt < nkt; kt++){
    __syncthreads();                       // previous compute done
    unsigned kb = (unsigned)kt * 128u;
    #pragma unroll
    for (int t = 0; t < 4; t++){
      gload_lds16(baseA + offA[t] + kb, (char*)ldsA + (size_t)(t*256 + tid)*16);
      gload_lds16(baseB + offB[t] + kb, (char*)ldsB + (size_t)(t*256 + tid)*16);
    }
    __syncthreads();                       // compiler drains vmcnt(0) here
    #pragma unroll
    for (int ks = 0; ks < 2; ks++){
      bf16x8 av[4], bv[4];
      #pragma unroll
      for (int mt = 0; mt < 4; mt++){
        int rl = wr*64 + mt*16 + ln;
        int ch = rl*8 + ((ks*4 + qr) ^ (rl & 7));
        av[mt] = *(const bf16x8*)((const char*)ldsA + ch*16);
      }
      #pragma unroll
      for (int nt = 0; nt < 4; nt++){
        int rl = wc*64 + nt*16 + ln;
        int ch = rl*8 + ((ks*4 + qr) ^ (rl & 7));
        bv[nt] = *(const bf16x8*)((const char*)ldsB + ch*16);
      }
      #pragma unroll
      for (int mt = 0; mt < 4; mt++)
        #pragma unroll
        for (int nt = 0; nt < 4; nt++)
          acc[mt][nt] = __builtin_amdgcn_mfma_f32_16x16x32_bf16(av[mt], bv[nt], acc[mt][nt], 0, 0, 0);
    }
  }

  if (part){
    // C layout: row = quad*4 + reg, col = lane&15 (per 16x16 tile). Plain sum-exp.
    #pragma unroll
    for (int mt = 0; mt < 4; mt++){
      #pragma unroll
      for (int r = 0; r < 4; r++){
        float ss = 0.f;
        #pragma unroll
        for (int nt = 0; nt < 4; nt++){
          int col = n0 + wc*64 + nt*16 + ln;
          if (col < N){
            float v = acc[mt][nt][r];
            ss += __expf(v);
            if (gatesp && col >= 10000){
              int row = row0 + wr*64 + mt*16 + qr*4 + r;
              gatesp[row*4 + (col - 10000)] = v;
            }
          }
        }
        ss += __shfl_xor(ss, 1, 64);
        ss += __shfl_xor(ss, 2, 64);
        ss += __shfl_xor(ss, 4, 64);
        ss += __shfl_xor(ss, 8, 64);
        if (ln == 0) msLds[wr*64 + mt*16 + qr*4 + r][wc] = ss;
      }
    }
    __syncthreads();
    if (tid < 128)
      part[(size_t)tileN*1024 + row0 + tid] = msLds[tid][0] + msLds[tid][1];
  } else {
    #pragma unroll
    for (int mt = 0; mt < 4; mt++)
      #pragma unroll
      for (int nt = 0; nt < 4; nt++)
        #pragma unroll
        for (int r = 0; r < 4; r++){
          int col = n0 + wc*64 + nt*16 + ln;
          if (col < N){
            int row = row0 + wr*64 + mt*16 + qr*4 + r;
            Cc[(size_t)row*ldc + col] = f2bf(acc[mt][nt][r]);
          }
        }
  }
}

// ---------------- LSE finalize: lse = log(sum of tile partials) ----------------
// wave-per-row (5120 waves); lanes stride tiles. part layout [tile][row].
struct LseTab { const float* base[5]; int ntiles[5]; float* lse; };

__global__ __launch_bounds__(256) void lse_reduce(LseTab t){
  int widx = blockIdx.x*4 + (threadIdx.x >> 6);   // 5120 waves: mat*1024 + row
  int lane = threadIdx.x & 63;
  int mat = widx >> 10, row = widx & 1023;
  const float* p = t.base[mat];
  int n = t.ntiles[mat];
  float s = 0.f;
  for (int i = lane; i < n; i += 64) s += p[(size_t)i*1024 + row];
  s = wave_sum(s);
  if (lane == 0) t.lse[mat*1024 + row] = __logf(s);
}

// ------- row-centric per-target log-prob + fused row loss: one block per row -------
// 16 groups of 16 lanes; each group owns 8 targets. Uniform 8-iteration dot
// (k = gl*8 + it*128, clamped address + select-zero for short rows) -> no
// branch divergence across groups; consecutive targets' loads pipeline.
struct GatherArgs {
  const u16* Xb; const u16* Hb; const u16* Hact; const u16* Ob;
  const float* lse; const float* gates; const int* targets;
  const float* discard; float* psamp;
};

__global__ __launch_bounds__(256) void gather_rows(GatherArgs g){
  __shared__ __attribute__((aligned(16))) u16 xr[1024];
  __shared__ __attribute__((aligned(16))) u16 hr[960];
  __shared__ __attribute__((aligned(16))) int tg[128];
  __shared__ float ls[5], gs[4];
  __shared__ float lpv[128];
  __shared__ float sa[2], sw[2];

  int b = blockIdx.x;
  int tid = threadIdx.x;
  int w = tid >> 6, lane = tid & 63;
  int grp = tid >> 4, gl = tid & 15;      // 16 groups x 16 lanes

  if (tid < 128) ((u32x4*)xr)[tid] = ((const u32x4*)(g.Xb + (size_t)b*1024))[tid];
  else if (tid < 248) ((u32x4*)hr)[tid-128] = ((const u32x4*)(g.Hact + (size_t)b*960))[tid-128];
  if (tid < 32) ((u32x4*)tg)[tid] = ((const u32x4*)(g.targets + (size_t)b*128))[tid];
  if (tid < 5) ls[tid] = g.lse[tid*1024 + b];
  if (tid < 4) gs[tid] = g.gates[b*4 + tid];
  __syncthreads();

  for (int t = 0; t < 8; t++){
    int ti = grp*8 + t;
    int v = tg[ti];                        // group-uniform broadcast
    // branchless per-target parameters (cndmask chains, no VGPR arrays)
    bool head = v < 10000;
    int c    = (v >= 20000) + (v >= 40000) + (v >= 80000);      // cluster idx
    int offv = head ? 0 : (c==0 ? 10000 : c==1 ? 20000 : c==2 ? 40000 : 80000);
    int len  = head ? 1024 : (c==0 ? 512 : c==1 ? 256 : c==2 ? 128 : 64);
    int hoff = c==0 ? 0 : c==1 ? 512 : c==2 ? 768 : 896;
    size_t obo = (size_t)c * 5120000u;     // 0,5.12M,10.24M,15.36M
    const u16* alds = head ? xr : hr + hoff;
    const u16* brow = head ? g.Hb + (size_t)v*1024
                           : g.Ob + obo + (size_t)(v - offv)*len;
    float s = 0.f;
    #pragma unroll
    for (int it = 0; it < 8; it++){
      int k  = gl*8 + it*128;
      int kc = k < len ? k : 0;            // clamp: excess iters hit L1
      u32x4 va = *(const u32x4*)(alds + kc);
      u32x4 vb = *(const u32x4*)(brow + kc);
      float p = 0.f;
      #pragma unroll
      for (int i = 0; i < 4; i++){
        unsigned ua = va[i], ub = vb[i];
        p = fmaf(__uint_as_float(ua << 16),         __uint_as_float(ub << 16),         p);
        p = fmaf(__uint_as_float(ua & 0xFFFF0000u), __uint_as_float(ub & 0xFFFF0000u), p);
      }
      s += (k < len) ? p : 0.f;
    }
    // 16-lane group reduce (xor < 16 stays inside the group)
    s += __shfl_xor(s, 1, 64);
    s += __shfl_xor(s, 2, 64);
    s += __shfl_xor(s, 4, 64);
    s += __shfl_xor(s, 8, 64);
    float bias = head ? -ls[0] : (gs[c] - ls[0] - ls[c + 1]);   // LDS dyn-index ok
    if (gl == 0) lpv[ti] = s + bias;
  }
  __syncthreads();

  // fused row_loss: per-row weighted mean NLL (target_mask is all ones)
  if (tid < 128){
    int v = tg[tid];
    float wt = 1.0f - g.discard[v];
    float a  = -lpv[tid] * wt;
    float as = wave_sum(a), ws = wave_sum(wt);
    if (lane == 0){ sa[w] = as; sw[w] = ws; }
  }
  __syncthreads();
  if (tid == 0) g.psamp[b] = (sa[0] + sa[1]) / (sw[0] + sw[1]);
}

__global__ __launch_bounds__(256) void final_sum(const float* psamp, float* out){
  float s = 0.f;
  for (int i = threadIdx.x; i < 1024; i += 256) s += psamp[i];
  s = wave_sum(s);
  __shared__ float sb[4];
  if ((threadIdx.x & 63) == 0) sb[threadIdx.x >> 6] = s;
  __syncthreads();
  if (threadIdx.x == 0) out[0] = (sb[0] + sb[1] + sb[2] + sb[3]) / (1024.0f + 1e-5f);
}

// ---------------- host ----------------
extern "C" void kernel_launch(void* const* d_in, const int* in_sizes, int n_in,
                              void* d_out, int out_size, void* d_ws, size_t ws_size,
                              hipStream_t stream){
  (void)in_sizes; (void)n_in; (void)out_size; (void)ws_size;
  const float* features = (const float*)d_in[0];
  const float* head_w   = (const float*)d_in[1];
  const float* proj[4]  = {(const float*)d_in[2], (const float*)d_in[4],
                           (const float*)d_in[6], (const float*)d_in[8]};
  const float* outw[4]  = {(const float*)d_in[3], (const float*)d_in[5],
                           (const float*)d_in[7], (const float*)d_in[9]};
  const float* discard  = (const float*)d_in[10];
  const int*   targets  = (const int*)d_in[11];
  float* out = (float*)d_out;

  char* wsp = (char*)d_ws;
  size_t off = 0;
  auto carve = [&](size_t bytes)->char*{
    char* p = wsp + off; off += (bytes + 255) & ~(size_t)255; return p;
  };
  u16* Xb     = (u16*)carve(1024ull*1024*2);
  u16* Hb     = (u16*)carve(10004ull*1024*2);
  u16* Pb     = (u16*)carve(960ull*1024*2);
  u16* Ob     = (u16*)carve(16640000ull*2);
  u16* Hact   = (u16*)carve(1024ull*960*2);
  float* part = (float*)carve(803840ull*4);   // 785 tiles x 1024 rows
  float* lse  = (float*)carve(5*1024*4);
  float* gates= (float*)carve(4096*4);
  float* psamp= (float*)carve(1024*4);

  // launch 1: convert all f32 operands to bf16
  CvtTab ct{};
  const float* srcs[10] = {features, head_w, proj[0], proj[1], proj[2], proj[3],
                           outw[0], outw[1], outw[2], outw[3]};
  u16* dsts[10] = {Xb, Hb, Pb, Pb + 512*1024, Pb + 768*1024, Pb + 896*1024,
                   Ob, Ob + 5120000, Ob + 10240000, Ob + 15360000};
  unsigned counts[10] = {1048576u, 10244096u, 524288u, 262144u, 131072u, 65536u,
                         5120000u, 5120000u, 5120000u, 1280000u};
  unsigned pre = 0;
  for (int i = 0; i < 10; i++){
    ct.s[i].src = srcs[i]; ct.s[i].dst = dsts[i]; ct.s[i].start = pre;
    pre += counts[i] / 8;
  }
  ct.total = pre;  // 3,614,464 chunks
  cvt_bf16<<<dim3(4096), dim3(256), 0, stream>>>(ct);

  float* pHead = part;
  float* pC0 = part + 80896;    // 79*1024
  float* pC1 = part + 161792;   // 158*1024
  float* pC2 = part + 322560;   // 315*1024
  float* pC3 = part + 643072;   // 628*1024

  // launch 2: proj GEMMs (bf16 C -> Hact); small, must precede cluster segs
  GTab tp{};
  tp.nseg = 4; tp.swz = 0;
  tp.seg[0] = {Xb, Pb,            nullptr, Hact,       nullptr, 1024, 512, 1024, 4, 0, 960};
  tp.seg[1] = {Xb, Pb + 512*1024, nullptr, Hact + 512, nullptr, 1024, 256, 1024, 2, 4, 960};
  tp.seg[2] = {Xb, Pb + 768*1024, nullptr, Hact + 768, nullptr, 1024, 128, 1024, 1, 6, 960};
  tp.seg[3] = {Xb, Pb + 896*1024, nullptr, Hact + 896, nullptr, 1024, 64,  1024, 1, 7, 960};
  gemm_all<<<dim3(8, 8), dim3(256), 0, stream>>>(tp);

  // launch 3: mega — head + all 4 cluster GEMMs (sum-exp partials), 6280 blocks
  GTab tm{};
  tm.nseg = 5; tm.swz = 1;
  tm.seg[0] = {Xb,         Hb,            pHead, nullptr, gates,   1024, 10004, 1024, 79,  0,   0};
  tm.seg[1] = {Hact,       Ob,            pC0,   nullptr, nullptr, 960,  10000, 512,  79,  79,  0};
  tm.seg[2] = {Hact + 512, Ob + 5120000,  pC1,   nullptr, nullptr, 960,  20000, 256,  157, 158, 0};
  tm.seg[3] = {Hact + 768, Ob + 10240000, pC2,   nullptr, nullptr, 960,  40000, 128,  313, 315, 0};
  tm.seg[4] = {Hact + 896, Ob + 15360000, pC3,   nullptr, nullptr, 960,  20000, 64,   157, 628, 0};
  gemm_all<<<dim3(8, 785), dim3(256), 0, stream>>>(tm);

  // launch 4: LSE finalize
  LseTab lt{};
  lt.base[0] = pHead; lt.base[1] = pC0; lt.base[2] = pC1; lt.base[3] = pC2; lt.base[4] = pC3;
  lt.ntiles[0] = 79; lt.ntiles[1] = 79; lt.ntiles[2] = 157; lt.ntiles[3] = 313; lt.ntiles[4] = 157;
  lt.lse = lse;
  lse_reduce<<<dim3(1280), dim3(256), 0, stream>>>(lt);

  // launch 5: gather (target log-probs + fused row loss)
  GatherArgs ga{Xb, Hb, Hact, Ob, lse, gates, targets, discard, psamp};
  gather_rows<<<dim3(1024), dim3(256), 0, stream>>>(ga);

  // launch 6: final reduction
  final_sum<<<dim3(1), dim3(256), 0, stream>>>(psamp, out);
}

// Round 8
// 296.628 us; speedup vs baseline: 1.1675x; 1.0104x over previous
//
#include <hip/hip_runtime.h>
#include <cstdint>

// AdaptiveLoss: adaptive-softmax NLL.  5 launches:
//   1. cvt_bf16   : f32->bf16 for all operands (10 segments, 4096 blocks).
//   2. gemm_all   : proj GEMMs (bf16 C -> Hact), grid (8,8).
//   3. gemm_all   : single mega (head + c0..c3, 6280 blocks) -> sum-exp
//                   partials part[row][785] (flat per-row) + head gates.
//   4. gather_rows: in-block LSE (contiguous 785-float read per row) +
//                   16-lane-group per-target log-prob + fused row loss.
//   5. final_sum.
// R8 vs R7 (299.7 us): part layout -> row-major [1024][785]. Evidence: the
// [tile][row] transpose (R2) never helped the mega (94.1 vs 94.7 us with
// 26.5 vs 3.2 MB WRITE -- stores fully hidden) but it serialized LSE reads.
// Flat per-row layout makes each gather block's LSE a coalesced contiguous
// read (~3 floats/thread), so lse_reduce is deleted (launch + gap ~10 us).
// R4's fold attempt failed only because of the scattered layout.

typedef unsigned short u16;
typedef __attribute__((ext_vector_type(4))) float f32x4;
typedef __attribute__((ext_vector_type(8))) __bf16 bf16x8;
typedef __attribute__((ext_vector_type(4))) unsigned int u32x4;

__device__ __forceinline__ u16 f2bf(float f){
  unsigned u = __float_as_uint(f);
  u += 0x7FFFu + ((u >> 16) & 1u);   // RNE
  return (u16)(u >> 16);
}

__device__ __forceinline__ float wave_sum(float v){
  #pragma unroll
  for (int d = 1; d < 64; d <<= 1) v += __shfl_xor(v, d, 64);
  return v;
}

// async global->LDS, 16B per lane. LDS dest must be wave-uniform base
// (HW adds lane*16); global src is per-lane (carries the XOR pre-swizzle).
__device__ __forceinline__ void gload_lds16(const void* g, void* l){
  __builtin_amdgcn_global_load_lds(
      (const __attribute__((address_space(1))) unsigned int*)g,
      (__attribute__((address_space(3))) unsigned int*)l, 16, 0, 0);
}

// ---------------- convert f32 -> bf16 (10 segments, one launch) ----------------
struct CvtSeg { const float* src; u16* dst; unsigned start; }; // start in 8-elem chunks
struct CvtTab { CvtSeg s[10]; unsigned total; };

__global__ __launch_bounds__(256) void cvt_bf16(CvtTab t){
  unsigned stride = gridDim.x * blockDim.x;
  for (unsigned c = blockIdx.x*blockDim.x + threadIdx.x; c < t.total; c += stride){
    int si = 0;
    #pragma unroll
    for (int i = 1; i < 10; i++) if (c >= t.s[i].start) si = i;
    unsigned lo = c - t.s[si].start;
    const float4* sp = (const float4*)t.s[si].src + (size_t)lo*2;
    float4 f0 = sp[0], f1 = sp[1];
    uint4 d;
    d.x = (unsigned)f2bf(f0.x) | ((unsigned)f2bf(f0.y) << 16);
    d.y = (unsigned)f2bf(f0.z) | ((unsigned)f2bf(f0.w) << 16);
    d.z = (unsigned)f2bf(f1.x) | ((unsigned)f2bf(f1.y) << 16);
    d.w = (unsigned)f2bf(f1.z) | ((unsigned)f2bf(f1.w) << 16);
    ((uint4*)t.s[si].dst)[lo] = d;
  }
}

// ------- unified GEMM: C = A[MxK] * B[NxK]^T, 128x128 tile, BK=64 -------
// 4 waves 2x2; global_load_lds staging. part!=null -> per-(row,tile) sum-exp
// partials, layout part[row*ldc + tileN] (ldc = 785 global row stride, part
// pre-offset by the segment's global tile base); else bf16 C store (ldc).
// gates!=null (head): cols>=10000 -> gates[row*4+i].
struct GSeg { const u16* A; const u16* B; float* part; u16* C; float* gates;
              int lda, N, K, ntiles, tileStart, ldc; };
struct GTab { GSeg seg[5]; int nseg; int swz; };

__global__ __launch_bounds__(256, 4) void gemm_all(GTab tab){
  __shared__ __attribute__((aligned(16))) u16 ldsA[128*64];
  __shared__ __attribute__((aligned(16))) u16 ldsB[128*64];
  __shared__ float msLds[128][2];

  int bx = blockIdx.x, by = blockIdx.y;
  if (tab.swz){
    // bijective XCD swizzle, grid (8, nby): hardware XCD ~ flat%8.
    int flat = by * 8 + bx;
    int xcd = flat & 7, j = flat >> 3;
    by = (j >> 3) * 8 + xcd;
    bx = j & 7;
    if (by >= (int)gridDim.y){ by = j; bx = xcd; }  // bijective tail patch
  }

  int s = 0;
  #pragma unroll
  for (int i = 1; i < 5; i++)
    if (i < tab.nseg && by >= tab.seg[i].tileStart) s = i;
  const u16* Ab = tab.seg[s].A;
  const u16* Bb = tab.seg[s].B;
  float* part   = tab.seg[s].part;
  u16* Cc       = tab.seg[s].C;
  float* gatesp = tab.seg[s].gates;
  int lda = tab.seg[s].lda, N = tab.seg[s].N, K = tab.seg[s].K;
  int ldc = tab.seg[s].ldc;
  int tileN = by - tab.seg[s].tileStart;
  int n0 = tileN * 128;
  int row0 = bx * 128;

  int tid = threadIdx.x;
  int wid = tid >> 6, lane = tid & 63;
  int wr = wid >> 1, wc = wid & 1;
  int qr = lane >> 4, ln = lane & 15;

  // staging: 1024 chunks (16B) per matrix, 4 per thread; XOR swizzle applied
  // to the GLOBAL source k-chunk, LDS written linearly.
  const char* baseA = (const char*)(Ab + (size_t)row0*lda);
  const char* baseB = (const char*)Bb;
  unsigned offA[4], offB[4];
  #pragma unroll
  for (int t = 0; t < 4; t++){
    int c = t*256 + tid, row = c >> 3, jj = (c & 7) ^ (row & 7);
    offA[t] = (unsigned)(row*lda + jj*8) * 2u;
    int nr = n0 + row; if (nr >= N) nr = N - 1;    // clamp; masked in epilogue
    offB[t] = (unsigned)(nr*K + jj*8) * 2u;
  }

  f32x4 acc[4][4];
  const f32x4 zero = {0.f, 0.f, 0.f, 0.f};
  #pragma unroll
  for (int i = 0; i < 4; i++)
    #pragma unroll
    for (int j = 0; j < 4; j++) acc[i][j] = zero;

  int nkt = K >> 6;
  for (int kt = 0; kt < nkt; kt++){
    __syncthreads();                       // previous compute done
    unsigned kb = (unsigned)kt * 128u;
    #pragma unroll
    for (int t = 0; t < 4; t++){
      gload_lds16(baseA + offA[t] + kb, (char*)ldsA + (size_t)(t*256 + tid)*16);
      gload_lds16(baseB + offB[t] + kb, (char*)ldsB + (size_t)(t*256 + tid)*16);
    }
    __syncthreads();                       // compiler drains vmcnt(0) here
    #pragma unroll
    for (int ks = 0; ks < 2; ks++){
      bf16x8 av[4], bv[4];
      #pragma unroll
      for (int mt = 0; mt < 4; mt++){
        int rl = wr*64 + mt*16 + ln;
        int ch = rl*8 + ((ks*4 + qr) ^ (rl & 7));
        av[mt] = *(const bf16x8*)((const char*)ldsA + ch*16);
      }
      #pragma unroll
      for (int nt = 0; nt < 4; nt++){
        int rl = wc*64 + nt*16 + ln;
        int ch = rl*8 + ((ks*4 + qr) ^ (rl & 7));
        bv[nt] = *(const bf16x8*)((const char*)ldsB + ch*16);
      }
      #pragma unroll
      for (int mt = 0; mt < 4; mt++)
        #pragma unroll
        for (int nt = 0; nt < 4; nt++)
          acc[mt][nt] = __builtin_amdgcn_mfma_f32_16x16x32_bf16(av[mt], bv[nt], acc[mt][nt], 0, 0, 0);
    }
  }

  if (part){
    // C layout: row = quad*4 + reg, col = lane&15 (per 16x16 tile). Plain sum-exp.
    #pragma unroll
    for (int mt = 0; mt < 4; mt++){
      #pragma unroll
      for (int r = 0; r < 4; r++){
        float ss = 0.f;
        #pragma unroll
        for (int nt = 0; nt < 4; nt++){
          int col = n0 + wc*64 + nt*16 + ln;
          if (col < N){
            float v = acc[mt][nt][r];
            ss += __expf(v);
            if (gatesp && col >= 10000){
              int row = row0 + wr*64 + mt*16 + qr*4 + r;
              gatesp[row*4 + (col - 10000)] = v;
            }
          }
        }
        ss += __shfl_xor(ss, 1, 64);
        ss += __shfl_xor(ss, 2, 64);
        ss += __shfl_xor(ss, 4, 64);
        ss += __shfl_xor(ss, 8, 64);
        if (ln == 0) msLds[wr*64 + mt*16 + qr*4 + r][wc] = ss;
      }
    }
    __syncthreads();
    if (tid < 128)
      part[(size_t)(row0 + tid)*ldc + tileN] = msLds[tid][0] + msLds[tid][1];
  } else {
    #pragma unroll
    for (int mt = 0; mt < 4; mt++)
      #pragma unroll
      for (int nt = 0; nt < 4; nt++)
        #pragma unroll
        for (int r = 0; r < 4; r++){
          int col = n0 + wc*64 + nt*16 + ln;
          if (col < N){
            int row = row0 + wr*64 + mt*16 + qr*4 + r;
            Cc[(size_t)row*ldc + col] = f2bf(acc[mt][nt][r]);
          }
        }
  }
}

// ------- row-centric: in-block LSE + per-target log-prob + fused row loss -------
// part is flat [1024 rows][785 global tiles]; segment boundaries within a row:
// head 0..78, c0 79..157, c1 158..314, c2 315..627, c3 628..784.
struct GatherArgs {
  const u16* Xb; const u16* Hb; const u16* Hact; const u16* Ob;
  const float* part; const float* gates; const int* targets;
  const float* discard; float* psamp;
};

__global__ __launch_bounds__(256) void gather_rows(GatherArgs g){
  __shared__ __attribute__((aligned(16))) u16 xr[1024];
  __shared__ __attribute__((aligned(16))) u16 hr[960];
  __shared__ __attribute__((aligned(16))) int tg[128];
  __shared__ float sLse[4][5];
  __shared__ float ls[5], gs[4];
  __shared__ float lpv[128];
  __shared__ float sa[2], sw[2];

  int b = blockIdx.x;
  int tid = threadIdx.x;
  int w = tid >> 6, lane = tid & 63;
  int grp = tid >> 4, gl = tid & 15;      // 16 groups x 16 lanes

  if (tid < 128) ((u32x4*)xr)[tid] = ((const u32x4*)(g.Xb + (size_t)b*1024))[tid];
  else if (tid < 248) ((u32x4*)hr)[tid-128] = ((const u32x4*)(g.Hact + (size_t)b*960))[tid-128];
  if (tid < 32) ((u32x4*)tg)[tid] = ((const u32x4*)(g.targets + (size_t)b*128))[tid];
  if (tid < 4) gs[tid] = g.gates[b*4 + tid];

  // in-block LSE: contiguous coalesced read of this row's 785 partials
  {
    const float* pr = g.part + (size_t)b*785;
    float p0=0.f, p1=0.f, p2=0.f, p3=0.f, p4=0.f;
    for (int j = tid; j < 785; j += 256){
      float v = pr[j];
      if      (j <  79) p0 += v;
      else if (j < 158) p1 += v;
      else if (j < 315) p2 += v;
      else if (j < 628) p3 += v;
      else              p4 += v;
    }
    p0 = wave_sum(p0); p1 = wave_sum(p1); p2 = wave_sum(p2);
    p3 = wave_sum(p3); p4 = wave_sum(p4);
    if (lane == 0){
      sLse[w][0]=p0; sLse[w][1]=p1; sLse[w][2]=p2; sLse[w][3]=p3; sLse[w][4]=p4;
    }
  }
  __syncthreads();
  if (tid < 5)
    ls[tid] = __logf(sLse[0][tid] + sLse[1][tid] + sLse[2][tid] + sLse[3][tid]);
  __syncthreads();

  for (int t = 0; t < 8; t++){
    int ti = grp*8 + t;
    int v = tg[ti];                        // group-uniform broadcast
    // branchless per-target parameters (cndmask chains, no VGPR arrays)
    bool head = v < 10000;
    int c    = (v >= 20000) + (v >= 40000) + (v >= 80000);      // cluster idx
    int offv = head ? 0 : (c==0 ? 10000 : c==1 ? 20000 : c==2 ? 40000 : 80000);
    int len  = head ? 1024 : (c==0 ? 512 : c==1 ? 256 : c==2 ? 128 : 64);
    int hoff = c==0 ? 0 : c==1 ? 512 : c==2 ? 768 : 896;
    size_t obo = (size_t)c * 5120000u;     // 0,5.12M,10.24M,15.36M
    const u16* alds = head ? xr : hr + hoff;
    const u16* brow = head ? g.Hb + (size_t)v*1024
                           : g.Ob + obo + (size_t)(v - offv)*len;
    float s = 0.f;
    #pragma unroll
    for (int it = 0; it < 8; it++){
      int k  = gl*8 + it*128;
      int kc = k < len ? k : 0;            // clamp: excess iters hit L1
      u32x4 va = *(const u32x4*)(alds + kc);
      u32x4 vb = *(const u32x4*)(brow + kc);
      float p = 0.f;
      #pragma unroll
      for (int i = 0; i < 4; i++){
        unsigned ua = va[i], ub = vb[i];
        p = fmaf(__uint_as_float(ua << 16),         __uint_as_float(ub << 16),         p);
        p = fmaf(__uint_as_float(ua & 0xFFFF0000u), __uint_as_float(ub & 0xFFFF0000u), p);
      }
      s += (k < len) ? p : 0.f;
    }
    // 16-lane group reduce (xor < 16 stays inside the group)
    s += __shfl_xor(s, 1, 64);
    s += __shfl_xor(s, 2, 64);
    s += __shfl_xor(s, 4, 64);
    s += __shfl_xor(s, 8, 64);
    float bias = head ? -ls[0] : (gs[c] - ls[0] - ls[c + 1]);   // LDS dyn-index ok
    if (gl == 0) lpv[ti] = s + bias;
  }
  __syncthreads();

  // fused row_loss: per-row weighted mean NLL (target_mask is all ones)
  if (tid < 128){
    int v = tg[tid];
    float wt = 1.0f - g.discard[v];
    float a  = -lpv[tid] * wt;
    float as = wave_sum(a), ws = wave_sum(wt);
    if (lane == 0){ sa[w] = as; sw[w] = ws; }
  }
  __syncthreads();
  if (tid == 0) g.psamp[b] = (sa[0] + sa[1]) / (sw[0] + sw[1]);
}

__global__ __launch_bounds__(256) void final_sum(const float* psamp, float* out){
  float s = 0.f;
  for (int i = threadIdx.x; i < 1024; i += 256) s += psamp[i];
  s = wave_sum(s);
  __shared__ float sb[4];
  if ((threadIdx.x & 63) == 0) sb[threadIdx.x >> 6] = s;
  __syncthreads();
  if (threadIdx.x == 0) out[0] = (sb[0] + sb[1] + sb[2] + sb[3]) / (1024.0f + 1e-5f);
}

// ---------------- host ----------------
extern "C" void kernel_launch(void* const* d_in, const int* in_sizes, int n_in,
                              void* d_out, int out_size, void* d_ws, size_t ws_size,
                              hipStream_t stream){
  (void)in_sizes; (void)n_in; (void)out_size; (void)ws_size;
  const float* features = (const float*)d_in[0];
  const float* head_w   = (const float*)d_in[1];
  const float* proj[4]  = {(const float*)d_in[2], (const float*)d_in[4],
                           (const float*)d_in[6], (const float*)d_in[8]};
  const float* outw[4]  = {(const float*)d_in[3], (const float*)d_in[5],
                           (const float*)d_in[7], (const float*)d_in[9]};
  const float* discard  = (const float*)d_in[10];
  const int*   targets  = (const int*)d_in[11];
  float* out = (float*)d_out;

  char* wsp = (char*)d_ws;
  size_t off = 0;
  auto carve = [&](size_t bytes)->char*{
    char* p = wsp + off; off += (bytes + 255) & ~(size_t)255; return p;
  };
  u16* Xb     = (u16*)carve(1024ull*1024*2);
  u16* Hb     = (u16*)carve(10004ull*1024*2);
  u16* Pb     = (u16*)carve(960ull*1024*2);
  u16* Ob     = (u16*)carve(16640000ull*2);
  u16* Hact   = (u16*)carve(1024ull*960*2);
  float* part = (float*)carve(803840ull*4);   // 1024 rows x 785 global tiles
  float* gates= (float*)carve(4096*4);
  float* psamp= (float*)carve(1024*4);

  // launch 1: convert all f32 operands to bf16
  CvtTab ct{};
  const float* srcs[10] = {features, head_w, proj[0], proj[1], proj[2], proj[3],
                           outw[0], outw[1], outw[2], outw[3]};
  u16* dsts[10] = {Xb, Hb, Pb, Pb + 512*1024, Pb + 768*1024, Pb + 896*1024,
                   Ob, Ob + 5120000, Ob + 10240000, Ob + 15360000};
  unsigned counts[10] = {1048576u, 10244096u, 524288u, 262144u, 131072u, 65536u,
                         5120000u, 5120000u, 5120000u, 1280000u};
  unsigned pre = 0;
  for (int i = 0; i < 10; i++){
    ct.s[i].src = srcs[i]; ct.s[i].dst = dsts[i]; ct.s[i].start = pre;
    pre += counts[i] / 8;
  }
  ct.total = pre;  // 3,614,464 chunks
  cvt_bf16<<<dim3(4096), dim3(256), 0, stream>>>(ct);

  // launch 2: proj GEMMs (bf16 C -> Hact); small, must precede cluster segs
  GTab tp{};
  tp.nseg = 4; tp.swz = 0;
  tp.seg[0] = {Xb, Pb,            nullptr, Hact,       nullptr, 1024, 512, 1024, 4, 0, 960};
  tp.seg[1] = {Xb, Pb + 512*1024, nullptr, Hact + 512, nullptr, 1024, 256, 1024, 2, 4, 960};
  tp.seg[2] = {Xb, Pb + 768*1024, nullptr, Hact + 768, nullptr, 1024, 128, 1024, 1, 6, 960};
  tp.seg[3] = {Xb, Pb + 896*1024, nullptr, Hact + 896, nullptr, 1024, 64,  1024, 1, 7, 960};
  gemm_all<<<dim3(8, 8), dim3(256), 0, stream>>>(tp);

  // launch 3: mega — head + all 4 cluster GEMMs, 6280 blocks.
  // part[row][785]: per-seg pointer = part + global tile base; ldc = 785.
  GTab tm{};
  tm.nseg = 5; tm.swz = 1;
  tm.seg[0] = {Xb,         Hb,            part,       nullptr, gates,   1024, 10004, 1024, 79,  0,   785};
  tm.seg[1] = {Hact,       Ob,            part + 79,  nullptr, nullptr, 960,  10000, 512,  79,  79,  785};
  tm.seg[2] = {Hact + 512, Ob + 5120000,  part + 158, nullptr, nullptr, 960,  20000, 256,  157, 158, 785};
  tm.seg[3] = {Hact + 768, Ob + 10240000, part + 315, nullptr, nullptr, 960,  40000, 128,  313, 315, 785};
  tm.seg[4] = {Hact + 896, Ob + 15360000, part + 628, nullptr, nullptr, 960,  20000, 64,   157, 628, 785};
  gemm_all<<<dim3(8, 785), dim3(256), 0, stream>>>(tm);

  // launch 4: gather (in-block LSE + target log-probs + fused row loss)
  GatherArgs ga{Xb, Hb, Hact, Ob, part, gates, targets, discard, psamp};
  gather_rows<<<dim3(1024), dim3(256), 0, stream>>>(ga);

  // launch 5: final reduction
  final_sum<<<dim3(1), dim3(256), 0, stream>>>(psamp, out);
}

// Round 9
// 292.123 us; speedup vs baseline: 1.1855x; 1.0154x over previous
//
#include <hip/hip_runtime.h>
#include <cstdint>

// AdaptiveLoss: adaptive-softmax NLL.  5 launches:
//   1. cvt_bf16   : f32->bf16 for all operands (10 segments, 4096 blocks).
//   2. gemm_all   : proj GEMMs (bf16 C -> Hact), grid (8,8).
//   3. gemm_all   : single mega (head + c0..c3, 6280 blocks) -> sum-exp
//                   partials part[row][785] (flat per-row) + head gates.
//   4. gather_rows: in-block LSE + cluster-sorted targets (ballot counting
//                   sort; loss is order-independent) + exact-trip-count dots
//                   (dotT<8/4/2/1> by cluster) + fused row loss.
//   5. final_sum.
// R9 vs R8 (296.6 us): gather only. The uniform 8-iter dot loaded 2KB per
// target regardless of row length (clamped iters still issue) -> 60% of
// targets wasted 8-16x issue slots; plus 2-group-per-wave divergence.
// Sort-by-cluster (order-free: psamp = sum(-lp*w)/sum(w)) + strided t*16+grp
// assignment makes branches wave-uniform; per-cluster unrolled dotT keeps ILP
// with exact trips. Mega and all other kernels frozen at R8.

typedef unsigned short u16;
typedef __attribute__((ext_vector_type(4))) float f32x4;
typedef __attribute__((ext_vector_type(8))) __bf16 bf16x8;
typedef __attribute__((ext_vector_type(4))) unsigned int u32x4;

__device__ __forceinline__ u16 f2bf(float f){
  unsigned u = __float_as_uint(f);
  u += 0x7FFFu + ((u >> 16) & 1u);   // RNE
  return (u16)(u >> 16);
}

__device__ __forceinline__ float wave_sum(float v){
  #pragma unroll
  for (int d = 1; d < 64; d <<= 1) v += __shfl_xor(v, d, 64);
  return v;
}

// async global->LDS, 16B per lane. LDS dest must be wave-uniform base
// (HW adds lane*16); global src is per-lane (carries the XOR pre-swizzle).
__device__ __forceinline__ void gload_lds16(const void* g, void* l){
  __builtin_amdgcn_global_load_lds(
      (const __attribute__((address_space(1))) unsigned int*)g,
      (__attribute__((address_space(3))) unsigned int*)l, 16, 0, 0);
}

// ---------------- convert f32 -> bf16 (10 segments, one launch) ----------------
struct CvtSeg { const float* src; u16* dst; unsigned start; }; // start in 8-elem chunks
struct CvtTab { CvtSeg s[10]; unsigned total; };

__global__ __launch_bounds__(256) void cvt_bf16(CvtTab t){
  unsigned stride = gridDim.x * blockDim.x;
  for (unsigned c = blockIdx.x*blockDim.x + threadIdx.x; c < t.total; c += stride){
    int si = 0;
    #pragma unroll
    for (int i = 1; i < 10; i++) if (c >= t.s[i].start) si = i;
    unsigned lo = c - t.s[si].start;
    const float4* sp = (const float4*)t.s[si].src + (size_t)lo*2;
    float4 f0 = sp[0], f1 = sp[1];
    uint4 d;
    d.x = (unsigned)f2bf(f0.x) | ((unsigned)f2bf(f0.y) << 16);
    d.y = (unsigned)f2bf(f0.z) | ((unsigned)f2bf(f0.w) << 16);
    d.z = (unsigned)f2bf(f1.x) | ((unsigned)f2bf(f1.y) << 16);
    d.w = (unsigned)f2bf(f1.z) | ((unsigned)f2bf(f1.w) << 16);
    ((uint4*)t.s[si].dst)[lo] = d;
  }
}

// ------- unified GEMM: C = A[MxK] * B[NxK]^T, 128x128 tile, BK=64 -------
// 4 waves 2x2; global_load_lds staging. part!=null -> per-(row,tile) sum-exp
// partials, layout part[row*ldc + tileN] (ldc = 785 global row stride, part
// pre-offset by the segment's global tile base); else bf16 C store (ldc).
// gates!=null (head): cols>=10000 -> gates[row*4+i].
struct GSeg { const u16* A; const u16* B; float* part; u16* C; float* gates;
              int lda, N, K, ntiles, tileStart, ldc; };
struct GTab { GSeg seg[5]; int nseg; int swz; };

__global__ __launch_bounds__(256, 4) void gemm_all(GTab tab){
  __shared__ __attribute__((aligned(16))) u16 ldsA[128*64];
  __shared__ __attribute__((aligned(16))) u16 ldsB[128*64];
  __shared__ float msLds[128][2];

  int bx = blockIdx.x, by = blockIdx.y;
  if (tab.swz){
    // bijective XCD swizzle, grid (8, nby): hardware XCD ~ flat%8.
    int flat = by * 8 + bx;
    int xcd = flat & 7, j = flat >> 3;
    by = (j >> 3) * 8 + xcd;
    bx = j & 7;
    if (by >= (int)gridDim.y){ by = j; bx = xcd; }  // bijective tail patch
  }

  int s = 0;
  #pragma unroll
  for (int i = 1; i < 5; i++)
    if (i < tab.nseg && by >= tab.seg[i].tileStart) s = i;
  const u16* Ab = tab.seg[s].A;
  const u16* Bb = tab.seg[s].B;
  float* part   = tab.seg[s].part;
  u16* Cc       = tab.seg[s].C;
  float* gatesp = tab.seg[s].gates;
  int lda = tab.seg[s].lda, N = tab.seg[s].N, K = tab.seg[s].K;
  int ldc = tab.seg[s].ldc;
  int tileN = by - tab.seg[s].tileStart;
  int n0 = tileN * 128;
  int row0 = bx * 128;

  int tid = threadIdx.x;
  int wid = tid >> 6, lane = tid & 63;
  int wr = wid >> 1, wc = wid & 1;
  int qr = lane >> 4, ln = lane & 15;

  // staging: 1024 chunks (16B) per matrix, 4 per thread; XOR swizzle applied
  // to the GLOBAL source k-chunk, LDS written linearly.
  const char* baseA = (const char*)(Ab + (size_t)row0*lda);
  const char* baseB = (const char*)Bb;
  unsigned offA[4], offB[4];
  #pragma unroll
  for (int t = 0; t < 4; t++){
    int c = t*256 + tid, row = c >> 3, jj = (c & 7) ^ (row & 7);
    offA[t] = (unsigned)(row*lda + jj*8) * 2u;
    int nr = n0 + row; if (nr >= N) nr = N - 1;    // clamp; masked in epilogue
    offB[t] = (unsigned)(nr*K + jj*8) * 2u;
  }

  f32x4 acc[4][4];
  const f32x4 zero = {0.f, 0.f, 0.f, 0.f};
  #pragma unroll
  for (int i = 0; i < 4; i++)
    #pragma unroll
    for (int j = 0; j < 4; j++) acc[i][j] = zero;

  int nkt = K >> 6;
  for (int kt = 0; kt < nkt; kt++){
    __syncthreads();                       // previous compute done
    unsigned kb = (unsigned)kt * 128u;
    #pragma unroll
    for (int t = 0; t < 4; t++){
      gload_lds16(baseA + offA[t] + kb, (char*)ldsA + (size_t)(t*256 + tid)*16);
      gload_lds16(baseB + offB[t] + kb, (char*)ldsB + (size_t)(t*256 + tid)*16);
    }
    __syncthreads();                       // compiler drains vmcnt(0) here
    #pragma unroll
    for (int ks = 0; ks < 2; ks++){
      bf16x8 av[4], bv[4];
      #pragma unroll
      for (int mt = 0; mt < 4; mt++){
        int rl = wr*64 + mt*16 + ln;
        int ch = rl*8 + ((ks*4 + qr) ^ (rl & 7));
        av[mt] = *(const bf16x8*)((const char*)ldsA + ch*16);
      }
      #pragma unroll
      for (int nt = 0; nt < 4; nt++){
        int rl = wc*64 + nt*16 + ln;
        int ch = rl*8 + ((ks*4 + qr) ^ (rl & 7));
        bv[nt] = *(const bf16x8*)((const char*)ldsB + ch*16);
      }
      #pragma unroll
      for (int mt = 0; mt < 4; mt++)
        #pragma unroll
        for (int nt = 0; nt < 4; nt++)
          acc[mt][nt] = __builtin_amdgcn_mfma_f32_16x16x32_bf16(av[mt], bv[nt], acc[mt][nt], 0, 0, 0);
    }
  }

  if (part){
    // C layout: row = quad*4 + reg, col = lane&15 (per 16x16 tile). Plain sum-exp.
    #pragma unroll
    for (int mt = 0; mt < 4; mt++){
      #pragma unroll
      for (int r = 0; r < 4; r++){
        float ss = 0.f;
        #pragma unroll
        for (int nt = 0; nt < 4; nt++){
          int col = n0 + wc*64 + nt*16 + ln;
          if (col < N){
            float v = acc[mt][nt][r];
            ss += __expf(v);
            if (gatesp && col >= 10000){
              int row = row0 + wr*64 + mt*16 + qr*4 + r;
              gatesp[row*4 + (col - 10000)] = v;
            }
          }
        }
        ss += __shfl_xor(ss, 1, 64);
        ss += __shfl_xor(ss, 2, 64);
        ss += __shfl_xor(ss, 4, 64);
        ss += __shfl_xor(ss, 8, 64);
        if (ln == 0) msLds[wr*64 + mt*16 + qr*4 + r][wc] = ss;
      }
    }
    __syncthreads();
    if (tid < 128)
      part[(size_t)(row0 + tid)*ldc + tileN] = msLds[tid][0] + msLds[tid][1];
  } else {
    #pragma unroll
    for (int mt = 0; mt < 4; mt++)
      #pragma unroll
      for (int nt = 0; nt < 4; nt++)
        #pragma unroll
        for (int r = 0; r < 4; r++){
          int col = n0 + wc*64 + nt*16 + ln;
          if (col < N){
            int row = row0 + wr*64 + mt*16 + qr*4 + r;
            Cc[(size_t)row*ldc + col] = f2bf(acc[mt][nt][r]);
          }
        }
  }
}

// ---- gather helpers: exact-trip unrolled dots (16-lane group, 128 elems/iter) ----
__device__ __forceinline__ float dot8pair(u32x4 va, u32x4 vb){
  float p = 0.f;
  #pragma unroll
  for (int i = 0; i < 4; i++){
    unsigned ua = va[i], ub = vb[i];
    p = fmaf(__uint_as_float(ua << 16),         __uint_as_float(ub << 16),         p);
    p = fmaf(__uint_as_float(ua & 0xFFFF0000u), __uint_as_float(ub & 0xFFFF0000u), p);
  }
  return p;
}

template<int T>
__device__ __forceinline__ float dotT(const u16* a, const u16* b, int gl){
  float s = 0.f;
  #pragma unroll
  for (int it = 0; it < T; it++){
    int k = gl*8 + it*128;
    s += dot8pair(*(const u32x4*)(a + k), *(const u32x4*)(b + k));
  }
  return s;
}

// len=64 variant: one iteration, upper 8 lanes masked
__device__ __forceinline__ float dot1m(const u16* a, const u16* b, int gl){
  int k = gl*8;
  int kc = k < 64 ? k : 0;
  float p = dot8pair(*(const u32x4*)(a + kc), *(const u32x4*)(b + kc));
  return k < 64 ? p : 0.f;
}

// ------- row-centric: in-block LSE + sorted per-target log-prob + row loss -------
// part is flat [1024 rows][785 global tiles]; segment boundaries within a row:
// head 0..78, c0 79..157, c1 158..314, c2 315..627, c3 628..784.
struct GatherArgs {
  const u16* Xb; const u16* Hb; const u16* Hact; const u16* Ob;
  const float* part; const float* gates; const int* targets;
  const float* discard; float* psamp;
};

__global__ __launch_bounds__(256) void gather_rows(GatherArgs g){
  __shared__ __attribute__((aligned(16))) u16 xr[1024];
  __shared__ __attribute__((aligned(16))) u16 hr[960];
  __shared__ __attribute__((aligned(16))) int tg[128];
  __shared__ int tgs[128];                // cluster-sorted targets
  __shared__ int cntW[2][5];              // per-wave bucket counts
  __shared__ float sLse[4][5];
  __shared__ float ls[5], gs[4];
  __shared__ float lpv[128];
  __shared__ float sa[2], sw[2];

  int b = blockIdx.x;
  int tid = threadIdx.x;
  int w = tid >> 6, lane = tid & 63;
  int grp = tid >> 4, gl = tid & 15;      // 16 groups x 16 lanes

  if (tid < 128) ((u32x4*)xr)[tid] = ((const u32x4*)(g.Xb + (size_t)b*1024))[tid];
  else if (tid < 248) ((u32x4*)hr)[tid-128] = ((const u32x4*)(g.Hact + (size_t)b*960))[tid-128];
  if (tid < 32) ((u32x4*)tg)[tid] = ((const u32x4*)(g.targets + (size_t)b*128))[tid];
  if (tid < 4) gs[tid] = g.gates[b*4 + tid];

  // in-block LSE: contiguous coalesced read of this row's 785 partials
  {
    const float* pr = g.part + (size_t)b*785;
    float p0=0.f, p1=0.f, p2=0.f, p3=0.f, p4=0.f;
    for (int j = tid; j < 785; j += 256){
      float v = pr[j];
      if      (j <  79) p0 += v;
      else if (j < 158) p1 += v;
      else if (j < 315) p2 += v;
      else if (j < 628) p3 += v;
      else              p4 += v;
    }
    p0 = wave_sum(p0); p1 = wave_sum(p1); p2 = wave_sum(p2);
    p3 = wave_sum(p3); p4 = wave_sum(p4);
    if (lane == 0){
      sLse[w][0]=p0; sLse[w][1]=p1; sLse[w][2]=p2; sLse[w][3]=p3; sLse[w][4]=p4;
    }
  }
  __syncthreads();                        // staging + sLse visible
  if (tid < 5)
    ls[tid] = __logf(sLse[0][tid] + sLse[1][tid] + sLse[2][tid] + sLse[3][tid]);

  // ---- counting sort by bucket (ballot/popcount); waves 2,3 mirror harmlessly ----
  int vb128 = tg[tid & 127];
  int bkt = (vb128 >= 10000) + (vb128 >= 20000) + (vb128 >= 40000) + (vb128 >= 80000);
  unsigned long long ltm = (1ULL << lane) - 1ULL;
  int rank = 0;
  #pragma unroll
  for (int c = 0; c < 5; c++){
    unsigned long long m = __ballot(bkt == c);
    if (bkt == c) rank = __popcll(m & ltm);
    if (lane == 0 && w < 2) cntW[w][c] = (int)__popcll(m);
  }
  __syncthreads();                        // cntW + ls visible
  if (tid < 128){
    int base = 0;
    #pragma unroll
    for (int c = 0; c < 5; c++)
      base += (c < bkt) ? (cntW[0][c] + cntW[1][c]) : 0;
    int pos = base + (w == 1 ? cntW[0][bkt] : 0) + rank;
    tgs[pos] = vb128;
  }
  __syncthreads();                        // tgs visible

  // ---- per-target log-prob: 16 consecutive sorted targets per iteration ----
  for (int t = 0; t < 8; t++){
    int ti = t*16 + grp;
    int v = tgs[ti];                      // group-uniform; wave-uniform cluster (sorted)
    bool head = v < 10000;
    int c = (v >= 20000) + (v >= 40000) + (v >= 80000);
    float s;
    if (head)       s = dotT<8>(xr,       g.Hb + (size_t)v*1024, gl);
    else if (c==0)  s = dotT<4>(hr,       g.Ob + (size_t)(v-10000)*512, gl);
    else if (c==1)  s = dotT<2>(hr + 512, g.Ob + 5120000u  + (size_t)(v-20000)*256, gl);
    else if (c==2)  s = dotT<1>(hr + 768, g.Ob + 10240000u + (size_t)(v-40000)*128, gl);
    else            s = dot1m  (hr + 896, g.Ob + 15360000u + (size_t)(v-80000)*64,  gl);
    // 16-lane group reduce (xor < 16 stays inside the group)
    s += __shfl_xor(s, 1, 64);
    s += __shfl_xor(s, 2, 64);
    s += __shfl_xor(s, 4, 64);
    s += __shfl_xor(s, 8, 64);
    float bias = head ? -ls[0] : (gs[c] - ls[0] - ls[c + 1]);   // LDS dyn-index ok
    if (gl == 0) lpv[ti] = s + bias;
  }
  __syncthreads();

  // fused row_loss: per-row weighted mean NLL (order-independent sum;
  // tgs/lpv pairing is consistent by index)
  if (tid < 128){
    int v = tgs[tid];
    float wt = 1.0f - g.discard[v];
    float a  = -lpv[tid] * wt;
    float as = wave_sum(a), ws = wave_sum(wt);
    if (lane == 0){ sa[w] = as; sw[w] = ws; }
  }
  __syncthreads();
  if (tid == 0) g.psamp[b] = (sa[0] + sa[1]) / (sw[0] + sw[1]);
}

__global__ __launch_bounds__(256) void final_sum(const float* psamp, float* out){
  float s = 0.f;
  for (int i = threadIdx.x; i < 1024; i += 256) s += psamp[i];
  s = wave_sum(s);
  __shared__ float sb[4];
  if ((threadIdx.x & 63) == 0) sb[threadIdx.x >> 6] = s;
  __syncthreads();
  if (threadIdx.x == 0) out[0] = (sb[0] + sb[1] + sb[2] + sb[3]) / (1024.0f + 1e-5f);
}

// ---------------- host ----------------
extern "C" void kernel_launch(void* const* d_in, const int* in_sizes, int n_in,
                              void* d_out, int out_size, void* d_ws, size_t ws_size,
                              hipStream_t stream){
  (void)in_sizes; (void)n_in; (void)out_size; (void)ws_size;
  const float* features = (const float*)d_in[0];
  const float* head_w   = (const float*)d_in[1];
  const float* proj[4]  = {(const float*)d_in[2], (const float*)d_in[4],
                           (const float*)d_in[6], (const float*)d_in[8]};
  const float* outw[4]  = {(const float*)d_in[3], (const float*)d_in[5],
                           (const float*)d_in[7], (const float*)d_in[9]};
  const float* discard  = (const float*)d_in[10];
  const int*   targets  = (const int*)d_in[11];
  float* out = (float*)d_out;

  char* wsp = (char*)d_ws;
  size_t off = 0;
  auto carve = [&](size_t bytes)->char*{
    char* p = wsp + off; off += (bytes + 255) & ~(size_t)255; return p;
  };
  u16* Xb     = (u16*)carve(1024ull*1024*2);
  u16* Hb     = (u16*)carve(10004ull*1024*2);
  u16* Pb     = (u16*)carve(960ull*1024*2);
  u16* Ob     = (u16*)carve(16640000ull*2);
  u16* Hact   = (u16*)carve(1024ull*960*2);
  float* part = (float*)carve(803840ull*4);   // 1024 rows x 785 global tiles
  float* gates= (float*)carve(4096*4);
  float* psamp= (float*)carve(1024*4);

  // launch 1: convert all f32 operands to bf16
  CvtTab ct{};
  const float* srcs[10] = {features, head_w, proj[0], proj[1], proj[2], proj[3],
                           outw[0], outw[1], outw[2], outw[3]};
  u16* dsts[10] = {Xb, Hb, Pb, Pb + 512*1024, Pb + 768*1024, Pb + 896*1024,
                   Ob, Ob + 5120000, Ob + 10240000, Ob + 15360000};
  unsigned counts[10] = {1048576u, 10244096u, 524288u, 262144u, 131072u, 65536u,
                         5120000u, 5120000u, 5120000u, 1280000u};
  unsigned pre = 0;
  for (int i = 0; i < 10; i++){
    ct.s[i].src = srcs[i]; ct.s[i].dst = dsts[i]; ct.s[i].start = pre;
    pre += counts[i] / 8;
  }
  ct.total = pre;  // 3,614,464 chunks
  cvt_bf16<<<dim3(4096), dim3(256), 0, stream>>>(ct);

  // launch 2: proj GEMMs (bf16 C -> Hact); small, must precede cluster segs
  GTab tp{};
  tp.nseg = 4; tp.swz = 0;
  tp.seg[0] = {Xb, Pb,            nullptr, Hact,       nullptr, 1024, 512, 1024, 4, 0, 960};
  tp.seg[1] = {Xb, Pb + 512*1024, nullptr, Hact + 512, nullptr, 1024, 256, 1024, 2, 4, 960};
  tp.seg[2] = {Xb, Pb + 768*1024, nullptr, Hact + 768, nullptr, 1024, 128, 1024, 1, 6, 960};
  tp.seg[3] = {Xb, Pb + 896*1024, nullptr, Hact + 896, nullptr, 1024, 64,  1024, 1, 7, 960};
  gemm_all<<<dim3(8, 8), dim3(256), 0, stream>>>(tp);

  // launch 3: mega — head + all 4 cluster GEMMs, 6280 blocks.
  // part[row][785]: per-seg pointer = part + global tile base; ldc = 785.
  GTab tm{};
  tm.nseg = 5; tm.swz = 1;
  tm.seg[0] = {Xb,         Hb,            part,       nullptr, gates,   1024, 10004, 1024, 79,  0,   785};
  tm.seg[1] = {Hact,       Ob,            part + 79,  nullptr, nullptr, 960,  10000, 512,  79,  79,  785};
  tm.seg[2] = {Hact + 512, Ob + 5120000,  part + 158, nullptr, nullptr, 960,  20000, 256,  157, 158, 785};
  tm.seg[3] = {Hact + 768, Ob + 10240000, part + 315, nullptr, nullptr, 960,  40000, 128,  313, 315, 785};
  tm.seg[4] = {Hact + 896, Ob + 15360000, part + 628, nullptr, nullptr, 960,  20000, 64,   157, 628, 785};
  gemm_all<<<dim3(8, 785), dim3(256), 0, stream>>>(tm);

  // launch 4: gather (in-block LSE + sorted target log-probs + row loss)
  GatherArgs ga{Xb, Hb, Hact, Ob, part, gates, targets, discard, psamp};
  gather_rows<<<dim3(1024), dim3(256), 0, stream>>>(ga);

  // launch 5: final reduction
  final_sum<<<dim3(1), dim3(256), 0, stream>>>(psamp, out);
}